// Round 6
// baseline (32.660 us; speedup 1.0000x reference)
//
#include <hip/hip_runtime.h>
#include <math.h>

// Problem constants (from reference setup): B=4, N=65536, M=128.
#define NPTS  65536
#define MBOX  128
#define NBATCH 4
#define GRID  16
#define NCELL (GRID * GRID)
#define CAP   MBOX            // worst case: every box overlaps one cell
#define INV   0.16f           // 1 / 6.25 m cell size over [-50, 50]

// Monotone f32 cell mapping — used identically for points and box bounds, so
// the +0.01 m pad on box bounds makes binning containment-conservative.
__device__ __forceinline__ int cell_of(float u) {
    int v = (int)floorf((u + 50.0f) * INV);
    v = v < 0 ? 0 : v;
    return v > (GRID - 1) ? (GRID - 1) : v;
}

// Build: one block per batch. Threads 0..127 derive per-box records
// {cx,cy,cz,hx,hy,hz,cos,sin} (accurate sinf/cosf — absmax=0 in R1-R5) into
// LDS; then one thread per cell scans boxes ascending and appends full 32 B
// records (plus u16 box id) for every box whose padded bounding disk touches
// the cell. Ascending append => first hit in scan order == smallest index.
// Lists padded to even length (duplicate last record; harmless under
// keep-first) so main can test unconditional pairs.
__global__ __launch_bounds__(256) void build_cells(const float* __restrict__ boxes,
                                                   float* __restrict__ recs,
                                                   unsigned short* __restrict__ ids,
                                                   int* __restrict__ cnts) {
    __shared__ float srec[MBOX * 8];
    __shared__ float srad[MBOX];
    int b = blockIdx.x;
    int t = threadIdx.x;
    if (t < MBOX) {
        const float* bx = boxes + ((size_t)b * MBOX + t) * 7;
        float hx = 0.5f * bx[3], hy = 0.5f * bx[4], hz = 0.5f * bx[5];
        float rz = bx[6];
        float* o = srec + t * 8;
        o[0] = bx[0]; o[1] = bx[1]; o[2] = bx[2];
        o[3] = hx;    o[4] = hy;    o[5] = hz;
        o[6] = cosf(rz); o[7] = sinf(rz);
        // circumradius of rotated rect + pad >> any f32 rounding wobble
        srad[t] = sqrtf(hx * hx + hy * hy) + 0.01f;
    }
    __syncthreads();

    int ci = t & (GRID - 1), cj = t >> 4;
    size_t cellbase = (size_t)b * NCELL + t;
    float* rdst = recs + cellbase * CAP * 8;
    unsigned short* idst = ids + cellbase * CAP;
    int cnt = 0;
    for (int m = 0; m < MBOX; ++m) {             // ascending => sorted lists
        float cx = srec[m * 8 + 0], cy = srec[m * 8 + 1];
        float r  = srad[m];
        int lox = cell_of(cx - r), hix = cell_of(cx + r);
        int loy = cell_of(cy - r), hiy = cell_of(cy + r);
        bool ov = (ci >= lox) & (ci <= hix) & (cj >= loy) & (cj <= hiy);
        if (ov) {
            float4 q0 = *(const float4*)(srec + m * 8);
            float4 q1 = *(const float4*)(srec + m * 8 + 4);
            *(float4*)(rdst + (size_t)cnt * 8)     = q0;
            *(float4*)(rdst + (size_t)cnt * 8 + 4) = q1;
            idst[cnt] = (unsigned short)m;
            ++cnt;
        }
    }
    if (cnt & 1) {                                // pad to even (cnt<=127 here)
        float4 q0 = *(const float4*)(rdst + (size_t)(cnt - 1) * 8);
        float4 q1 = *(const float4*)(rdst + (size_t)(cnt - 1) * 8 + 4);
        *(float4*)(rdst + (size_t)cnt * 8)     = q0;
        *(float4*)(rdst + (size_t)cnt * 8 + 4) = q1;
        idst[cnt] = idst[cnt - 1];
        ++cnt;
    }
    cnts[cellbase] = cnt;
}

// Main: 1 point/thread. Only the point's cell list (~2-4 entries avg) is
// tested instead of all 128 boxes. Records gathered from L1-resident lists
// (hot set ~20 KB/batch), pairs of boxes per iteration so 4 b128 gathers are
// in flight together. Keep-first select (no break) lets loads pipeline;
// ascending list order preserves argmax-first semantics. Test is bit-identical
// to R1-R5 (__f*_rn: mul, mul, add — no fma).
__global__ __launch_bounds__(256) void pib_main(const float* __restrict__ points,
                                                const float* __restrict__ recs,
                                                const unsigned short* __restrict__ ids,
                                                const int* __restrict__ cnts,
                                                float* __restrict__ out) {
    int b  = blockIdx.x >> 8;                     // 256 blocks per batch
    int pi = ((blockIdx.x & 255) << 8) + threadIdx.x;
    size_t gid = (size_t)b * NPTS + pi;

    const float* p = points + gid * 3;            // 4 B aligned only
    float px = p[0], py = p[1], pz = p[2];

    int cell = (cell_of(py) << 4) | cell_of(px);
    size_t cellbase = (size_t)b * NCELL + cell;
    int c = cnts[cellbase];                       // even by construction
    const float* rb = recs + cellbase * CAP * 8;

    int jhit = -1;
    for (int j = 0; j < c; j += 2) {
        float4 a0 = *(const float4*)(rb + (size_t)j * 8);
        float4 a1 = *(const float4*)(rb + (size_t)j * 8 + 4);
        float4 b0 = *(const float4*)(rb + (size_t)j * 8 + 8);
        float4 b1 = *(const float4*)(rb + (size_t)j * 8 + 12);
        {
            float lx = __fsub_rn(px, a0.x);
            float ly = __fsub_rn(py, a0.y);
            float lz = __fsub_rn(pz, a0.z);
            float X = __fadd_rn(__fmul_rn(lx, a1.z), __fmul_rn(ly, a1.w));
            float Y = __fsub_rn(__fmul_rn(ly, a1.z), __fmul_rn(lx, a1.w));
            bool in = (fabsf(X) <= a0.w) & (fabsf(Y) <= a1.x) & (fabsf(lz) <= a1.y);
            jhit = ((jhit < 0) & in) ? j : jhit;
        }
        {
            float lx = __fsub_rn(px, b0.x);
            float ly = __fsub_rn(py, b0.y);
            float lz = __fsub_rn(pz, b0.z);
            float X = __fadd_rn(__fmul_rn(lx, b1.z), __fmul_rn(ly, b1.w));
            float Y = __fsub_rn(__fmul_rn(ly, b1.z), __fmul_rn(lx, b1.w));
            bool in = (fabsf(X) <= b0.w) & (fabsf(Y) <= b1.x) & (fabsf(lz) <= b1.y);
            jhit = ((jhit < 0) & in) ? (j + 1) : jhit;
        }
    }

    float fidx = -1.0f;
    if (jhit >= 0) fidx = (float)ids[cellbase * CAP + jhit];  // once per point
    out[gid] = fidx;
}

extern "C" void kernel_launch(void* const* d_in, const int* in_sizes, int n_in,
                              void* d_out, int out_size, void* d_ws, size_t ws_size,
                              hipStream_t stream) {
    const float* points = (const float*)d_in[0];   // [B, N, 3] f32
    const float* boxes  = (const float*)d_in[1];   // [B, M, 7] f32
    float* out = (float*)d_out;                    // [B, N]    f32

    // d_ws layout: recs 4 MB | ids 256 KB | cnts 4 KB  (ws_size is ~268 MB)
    float* recs = (float*)d_ws;                                   // [B*256][CAP][8]
    unsigned short* ids = (unsigned short*)((char*)d_ws + (4u << 20));
    int* cnts = (int*)((char*)d_ws + (4u << 20) + (256u << 10));

    int n_points = in_sizes[0] / 3;                // B*N = 262144

    build_cells<<<NBATCH, 256, 0, stream>>>(boxes, recs, ids, cnts);

    int main_blocks = n_points / 256;              // 1024
    pib_main<<<main_blocks, 256, 0, stream>>>(points, recs, ids, cnts, out);
}

// Round 7
// 27.604 us; speedup vs baseline: 1.1832x; 1.1832x over previous
//
#include <hip/hip_runtime.h>
#include <math.h>

// Problem constants (from reference setup): B=4, N=65536, M=128.
#define NPTS  65536
#define MBOX  128
#define TPB   256
#define PPT   4               // points per thread: amortizes each LDS box read
#define PPB   (TPB * PPT)     // 1024 points per block
#define CHUNK 8               // boxes per load-batch (16 ds_read_b128 in flight)

// Single fused kernel, one dispatch. 256 blocks = exactly 1 block/CU.
// Per CU the LDS pipe now serves 4 waves x 256 ds_read_b128 (~2.6 us chip-wide)
// -- below the 5.5 us VALU floor, so VALU becomes the critical pipe.
// 4 points/thread = 4 independent dep chains; per 8-box chunk the 16 loads are
// followed by ~832 cyc of unrolled compute, so ds latency hides behind ILP
// (q[] is loop-local + unroll 2 -> compiler renames = natural double buffer).
// Descending m + overwrite: last write at smallest m == first containing box.
// __f*_rn blocks fp-contract (mul, mul, add -- no fma): absmax=0 in R1-R6.
__global__ __launch_bounds__(256) void pib_fused(const float* __restrict__ points,
                                                 const float* __restrict__ boxes,
                                                 float* __restrict__ out) {
    __shared__ float sraw[MBOX * 7];  // 3.5 KB raw boxes
    __shared__ float srec[MBOX * 8];  // 4.0 KB derived records

    const int blocksPerBatch = NPTS / PPB;            // 64
    int b   = blockIdx.x >> 6;
    int blk = blockIdx.x & 63;

    // Point loads first (independent of staging): 12 floats = 3x float4,
    // byte offset = tid*48 -> 16B aligned, coalesced.
    size_t p0 = (size_t)b * NPTS + (size_t)blk * PPB + (size_t)threadIdx.x * PPT;
    const float* p = points + p0 * 3;
    float4 v0 = *(const float4*)(p);
    float4 v1 = *(const float4*)(p + 4);
    float4 v2 = *(const float4*)(p + 8);
    float px0 = v0.x, py0 = v0.y, pz0 = v0.z;
    float px1 = v0.w, py1 = v1.x, pz1 = v1.y;
    float px2 = v1.z, py2 = v1.w, pz2 = v2.x;
    float px3 = v2.y, py3 = v2.z, pz3 = v2.w;

    // Stage raw boxes, coalesced.
    const float* bsrc = boxes + (size_t)b * MBOX * 7;
    for (int i = threadIdx.x; i < MBOX * 7; i += TPB) sraw[i] = bsrc[i];
    __syncthreads();

    // Derived records {cx,cy,cz,hx,hy,hz,cos,sin}; one thread per box.
    // stride-7 LDS reads are conflict-free (gcd(7,32)=1); one-time cost.
    if (threadIdx.x < MBOX) {
        const float* r = sraw + threadIdx.x * 7;
        float rz = r[6];
        float* o = srec + threadIdx.x * 8;
        o[0] = r[0]; o[1] = r[1]; o[2] = r[2];
        o[3] = 0.5f * r[3];   // exact, matches ref dims*0.5
        o[4] = 0.5f * r[4];
        o[5] = 0.5f * r[5];
        o[6] = cosf(rz);      // accurate libm: matches numpy (absmax=0 R1-R6)
        o[7] = sinf(rz);
    }
    __syncthreads();

    int idx0 = -1, idx1 = -1, idx2 = -1, idx3 = -1;

#define TEST4(Q0, Q1, M)                                                        \
    do {                                                                        \
        float cx = (Q0).x, cy = (Q0).y, cz = (Q0).z, hx = (Q0).w;               \
        float hy = (Q1).x, hz = (Q1).y, cr = (Q1).z, sr = (Q1).w;               \
        {   float lx = __fsub_rn(px0, cx), ly = __fsub_rn(py0, cy),             \
                  lz = __fsub_rn(pz0, cz);                                      \
            float X = __fadd_rn(__fmul_rn(lx, cr), __fmul_rn(ly, sr));          \
            float Y = __fsub_rn(__fmul_rn(ly, cr), __fmul_rn(lx, sr));          \
            bool in = (fabsf(X) <= hx) & (fabsf(Y) <= hy) & (fabsf(lz) <= hz);  \
            idx0 = in ? (M) : idx0; }                                           \
        {   float lx = __fsub_rn(px1, cx), ly = __fsub_rn(py1, cy),             \
                  lz = __fsub_rn(pz1, cz);                                      \
            float X = __fadd_rn(__fmul_rn(lx, cr), __fmul_rn(ly, sr));          \
            float Y = __fsub_rn(__fmul_rn(ly, cr), __fmul_rn(lx, sr));          \
            bool in = (fabsf(X) <= hx) & (fabsf(Y) <= hy) & (fabsf(lz) <= hz);  \
            idx1 = in ? (M) : idx1; }                                           \
        {   float lx = __fsub_rn(px2, cx), ly = __fsub_rn(py2, cy),             \
                  lz = __fsub_rn(pz2, cz);                                      \
            float X = __fadd_rn(__fmul_rn(lx, cr), __fmul_rn(ly, sr));          \
            float Y = __fsub_rn(__fmul_rn(ly, cr), __fmul_rn(lx, sr));          \
            bool in = (fabsf(X) <= hx) & (fabsf(Y) <= hy) & (fabsf(lz) <= hz);  \
            idx2 = in ? (M) : idx2; }                                           \
        {   float lx = __fsub_rn(px3, cx), ly = __fsub_rn(py3, cy),             \
                  lz = __fsub_rn(pz3, cz);                                      \
            float X = __fadd_rn(__fmul_rn(lx, cr), __fmul_rn(ly, sr));          \
            float Y = __fsub_rn(__fmul_rn(ly, cr), __fmul_rn(lx, sr));          \
            bool in = (fabsf(X) <= hx) & (fabsf(Y) <= hy) & (fabsf(lz) <= hz);  \
            idx3 = in ? (M) : idx3; }                                           \
    } while (0)

    #pragma unroll 2
    for (int base = MBOX - CHUNK; base >= 0; base -= CHUNK) {
        float4 q[2 * CHUNK];              // loop-local: unroll-2 renames = dbuf
        #pragma unroll
        for (int k = 0; k < CHUNK; ++k) {
            q[2 * k]     = ((const float4*)srec)[(base + k) * 2];     // uniform
            q[2 * k + 1] = ((const float4*)srec)[(base + k) * 2 + 1]; // -> bcast
        }
        #pragma unroll
        for (int k = CHUNK - 1; k >= 0; --k)   // descending within chunk
            TEST4(q[2 * k], q[2 * k + 1], base + k);
    }
#undef TEST4

    // 4 consecutive outputs per thread -> one 16B-aligned float4 store.
    *(float4*)(out + p0) =
        make_float4((float)idx0, (float)idx1, (float)idx2, (float)idx3);
}

extern "C" void kernel_launch(void* const* d_in, const int* in_sizes, int n_in,
                              void* d_out, int out_size, void* d_ws, size_t ws_size,
                              hipStream_t stream) {
    const float* points = (const float*)d_in[0];   // [B, N, 3] f32
    const float* boxes  = (const float*)d_in[1];   // [B, M, 7] f32
    float* out = (float*)d_out;                    // [B, N]    f32

    int n_points = in_sizes[0] / 3;                // B*N = 262144
    int main_blocks = n_points / PPB;              // 256 = 1 block/CU

    pib_fused<<<main_blocks, TPB, 0, stream>>>(points, boxes, out);
}